// Round 18
// baseline (413.720 us; speedup 1.0000x reference)
//
#include <hip/hip_runtime.h>
#include <hip/hip_bf16.h>
#include <math.h>

typedef short bf16x8 __attribute__((ext_vector_type(8)));
typedef float f32x4 __attribute__((ext_vector_type(4)));
typedef float f32x16 __attribute__((ext_vector_type(16)));

#define HEADS 16
#define HDIM 64
#define HID 1024
#define B_ 4
#define T_ 2048
#define BT_ (B_*T_)      /* 8192 */
#define N1 (7*HID)       /* 7168 */
#define K2 (5*HID)       /* 5120 */

#define SM_SCALE_LOG2E 0.18033688011111793f   /* 0.125 * log2(e), folded into q at gemm1 */

__device__ __forceinline__ float bf2f(unsigned short u) {
  union { unsigned int i; float f; } c; c.i = ((unsigned int)u) << 16; return c.f;
}
__device__ __forceinline__ unsigned short f2bf(float f) {
  __hip_bfloat16 h = __float2bfloat16(f);
  return __builtin_bit_cast(unsigned short, h);
}
__device__ __forceinline__ unsigned int cvt_pk_bf16(float a, float b) {
  unsigned int r;
  asm("v_cvt_pk_bf16_f32 %0, %1, %2" : "=v"(r) : "v"(a), "v"(b));
  return r;
}
// v_permlane32_swap_b32: D.lanes[32:63] <-> S.lanes[0:31]; writes BOTH regs.
__device__ __forceinline__ void permswap(unsigned int& d, unsigned int& s) {
  asm volatile("v_permlane32_swap_b32 %0, %1" : "+v"(d), "+v"(s));
}
__device__ __forceinline__ float gelu_fast(float x) {
  float y = 0.7978845608028654f * (x + 0.044715f * x * x * x);
  float e = exp2f(y * 2.8853900817779268f);       // exp(2y)
  float t = 1.f - 2.f / (e + 1.f);                 // tanh(y)
  return 0.5f * x * (1.f + t);
}

// ---------------- transpose + cast: in [R][C] f32 -> out [C][R] bf16 ----------------
__global__ __launch_bounds__(256) void tcast_kernel(const float* __restrict__ in,
                                                    unsigned short* __restrict__ out,
                                                    int R, int C) {
  __shared__ float tile[64][65];
  int tx = threadIdx.x & 63;
  int ty = threadIdx.x >> 6;
  long r0 = (long)blockIdx.y * 64;
  long c0 = (long)blockIdx.x * 64;
#pragma unroll
  for (int i = 0; i < 16; i++) {
    int r = ty + i * 4;
    tile[r][tx] = in[(r0 + r) * C + c0 + tx];
  }
  __syncthreads();
#pragma unroll
  for (int i = 0; i < 16; i++) {
    int rr = ty + i * 4;
    out[(c0 + rr) * R + r0 + tx] = f2bf(tile[tx][rr]);
  }
}

// ---------------- LayerNorm f32 -> bf16 ----------------
__global__ __launch_bounds__(256) void ln_kernel(const float* __restrict__ x,
                                                 const float* __restrict__ g,
                                                 const float* __restrict__ b,
                                                 unsigned short* __restrict__ xn) {
  int row = blockIdx.x, tid = threadIdx.x;
  float4 v = reinterpret_cast<const float4*>(x + (long)row * HID)[tid];
  float s = v.x + v.y + v.z + v.w;
  float sq = v.x * v.x + v.y * v.y + v.z * v.z + v.w * v.w;
#pragma unroll
  for (int off = 32; off > 0; off >>= 1) { s += __shfl_down(s, off); sq += __shfl_down(sq, off); }
  __shared__ float red[8];
  int wid = tid >> 6, lane = tid & 63;
  if (lane == 0) { red[wid] = s; red[4 + wid] = sq; }
  __syncthreads();
  if (tid == 0) {
    red[0] = red[0] + red[1] + red[2] + red[3];
    red[4] = red[4] + red[5] + red[6] + red[7];
  }
  __syncthreads();
  float mean = red[0] * (1.f / HID);
  float var  = red[4] * (1.f / HID) - mean * mean;
  float rstd = rsqrtf(var + 1e-5f);
  float4 gv = reinterpret_cast<const float4*>(g)[tid];
  float4 bv = reinterpret_cast<const float4*>(b)[tid];
  ushort4 o;
  o.x = f2bf((v.x - mean) * rstd * gv.x + bv.x);
  o.y = f2bf((v.y - mean) * rstd * gv.y + bv.y);
  o.z = f2bf((v.z - mean) * rstd * gv.z + bv.z);
  o.w = f2bf((v.w - mean) * rstd * gv.w + bv.w);
  reinterpret_cast<ushort4*>(xn + (long)row * HID)[tid] = o;
}

// ---------------- GEMM core: 128x128, BK=32, reg-staged dbuf, single barrier ----------
// (Proven 167-170 us on gemm1 across R13/R15/R16. Tile-scaling attempts (256^2 twice,
// 256x128 once) all regressed: this 2-phase schedule caps at ~31% MfmaUtil and larger
// tiles lose occupancy/lockstep. Do not touch.)
__device__ __forceinline__ void gemm_core_db(const unsigned short* __restrict__ A,
                                             const unsigned short* __restrict__ BT,
                                             unsigned short* As, unsigned short* Bs,
                                             int K, int lda, int ldb,
                                             long row0, long col0,
                                             int lane, int wid, f32x4 (&acc)[4][4]) {
  int l15 = lane & 15, lq = lane >> 4;
  int srow = lane >> 2;
  int schnk = lane & 3;
  int r0s = wid * 32 + srow;
  int r1s = r0s + 16;
  int slot0 = schnk ^ ((r0s >> 1) & 3);
  int slot1 = schnk ^ ((r1s >> 1) & 3);
  const unsigned short* a0 = A + (row0 + r0s) * (long)lda + schnk * 8;
  const unsigned short* a1 = A + (row0 + r1s) * (long)lda + schnk * 8;
  const unsigned short* b0 = BT + (col0 + r0s) * (long)ldb + schnk * 8;
  const unsigned short* b1 = BT + (col0 + r1s) * (long)ldb + schnk * 8;
  int wm = (wid & 1) * 64, wn = (wid >> 1) * 64;
  int NT = K / 32;

  bf16x8 ar0 = *reinterpret_cast<const bf16x8*>(a0);
  bf16x8 ar1 = *reinterpret_cast<const bf16x8*>(a1);
  bf16x8 br0 = *reinterpret_cast<const bf16x8*>(b0);
  bf16x8 br1 = *reinterpret_cast<const bf16x8*>(b1);
  *reinterpret_cast<bf16x8*>(&As[r0s * 32 + slot0 * 8]) = ar0;
  *reinterpret_cast<bf16x8*>(&As[r1s * 32 + slot1 * 8]) = ar1;
  *reinterpret_cast<bf16x8*>(&Bs[r0s * 32 + slot0 * 8]) = br0;
  *reinterpret_cast<bf16x8*>(&Bs[r1s * 32 + slot1 * 8]) = br1;
  ar0 = *reinterpret_cast<const bf16x8*>(a0 + 32);
  ar1 = *reinterpret_cast<const bf16x8*>(a1 + 32);
  br0 = *reinterpret_cast<const bf16x8*>(b0 + 32);
  br1 = *reinterpret_cast<const bf16x8*>(b1 + 32);
  __syncthreads();

  int cur = 0;
  for (int t = 0; t < NT; t++) {
    const unsigned short* Asr = As + cur * 4096;
    const unsigned short* Bsr = Bs + cur * 4096;
    bf16x8 af[4], bfv[4];
#pragma unroll
    for (int m = 0; m < 4; m++) {
      int r = wm + m * 16 + l15;
      af[m] = *reinterpret_cast<const bf16x8*>(&Asr[r * 32 + (lq ^ ((r >> 1) & 3)) * 8]);
    }
#pragma unroll
    for (int n = 0; n < 4; n++) {
      int r = wn + n * 16 + l15;
      bfv[n] = *reinterpret_cast<const bf16x8*>(&Bsr[r * 32 + (lq ^ ((r >> 1) & 3)) * 8]);
    }
    if (t + 1 < NT) {
      unsigned short* Asw = As + (cur ^ 1) * 4096;
      unsigned short* Bsw = Bs + (cur ^ 1) * 4096;
      *reinterpret_cast<bf16x8*>(&Asw[r0s * 32 + slot0 * 8]) = ar0;
      *reinterpret_cast<bf16x8*>(&Asw[r1s * 32 + slot1 * 8]) = ar1;
      *reinterpret_cast<bf16x8*>(&Bsw[r0s * 32 + slot0 * 8]) = br0;
      *reinterpret_cast<bf16x8*>(&Bsw[r1s * 32 + slot1 * 8]) = br1;
    }
    if (t + 2 < NT) {
      long ko = (long)(t + 2) * 32;
      ar0 = *reinterpret_cast<const bf16x8*>(a0 + ko);
      ar1 = *reinterpret_cast<const bf16x8*>(a1 + ko);
      br0 = *reinterpret_cast<const bf16x8*>(b0 + ko);
      br1 = *reinterpret_cast<const bf16x8*>(b1 + ko);
    }
#pragma unroll
    for (int m = 0; m < 4; m++)
#pragma unroll
      for (int n = 0; n < 4; n++)
        acc[m][n] = __builtin_amdgcn_mfma_f32_16x16x32_bf16(af[m], bfv[n], acc[m][n], 0, 0, 0);
    __syncthreads();
    cur ^= 1;
  }
}

// ---------------- GEMM1 with fused rotary / V-transpose / GELU epilogue (R10/R16) ------
__global__ __launch_bounds__(256) void gemm1_fused(const unsigned short* __restrict__ A,
                                                   const unsigned short* __restrict__ BT,
                                                   unsigned short* __restrict__ q_r,
                                                   unsigned short* __restrict__ k_r,
                                                   unsigned short* __restrict__ v_t,
                                                   unsigned short* __restrict__ C5) {
  __shared__ unsigned short smem[18432];
  unsigned short* As = smem;
  unsigned short* Bs = smem + 8192;
  int tid = threadIdx.x, lane = tid & 63, wid = tid >> 6;
  long row0 = (long)blockIdx.y * 128;
  long col0 = (long)blockIdx.x * 128;
  f32x4 acc[4][4] = {};
  gemm_core_db(A, BT, As, Bs, HID, HID, HID, row0, col0, lane, wid, acc);

  int wm = (wid & 1) * 64, wn = (wid >> 1) * 64;
  long row_base = row0 + wm;
  int b = (int)(row_base >> 11);
  int t_base = (int)(row_base & 2047);
  int col_base = (int)col0 + wn;
  int region = col_base >> 10;
  int l15 = lane & 15, lq = lane >> 4;

  if (region <= 1) {
    unsigned short* dst = (region == 0) ? q_r : k_r;
    float osc = (region == 0) ? SM_SCALE_LOG2E : 1.0f;
    int head = (col_base & 1023) >> 6;
    long obase = (long)(b * 16 + head) * T_ * 64;
    float fr[2];
    fr[0] = __expf(-(float)l15 * 0.28782313662425572f);
    fr[1] = __expf(-(float)(16 + l15) * 0.28782313662425572f);
#pragma unroll
    for (int m = 0; m < 4; m++) {
#pragma unroll
      for (int j = 0; j < 4; j++) {
        int t = t_base + m * 16 + lq * 4 + j;
#pragma unroll
        for (int n = 0; n < 2; n++) {
          float sn, cs;
          __sincosf((float)t * fr[n], &sn, &cs);
          float xl = acc[m][n][j], xh = acc[m][n + 2][j];
          int d = n * 16 + l15;
          dst[obase + (long)t * 64 + d]      = f2bf((xl * cs - xh * sn) * osc);
          dst[obase + (long)t * 64 + d + 32] = f2bf((xl * sn + xh * cs) * osc);
        }
      }
    }
  } else if (region == 2) {
    int head = (col_base & 1023) >> 6;
    unsigned short* vt = smem + wid * 4608;
#pragma unroll
    for (int m = 0; m < 4; m++)
#pragma unroll
      for (int n = 0; n < 4; n++)
#pragma unroll
        for (int j = 0; j < 4; j++)
          vt[(n * 16 + l15) * 72 + m * 16 + lq * 4 + j] = f2bf(acc[m][n][j]);
    long obase = (long)(b * 16 + head) * 64 * T_;
#pragma unroll
    for (int i = 0; i < 8; i++) {
      int d = i * 8 + (lane >> 3);
      int tl = (lane & 7) * 8;
      bf16x8 v = *reinterpret_cast<const bf16x8*>(&vt[d * 72 + tl]);
      *reinterpret_cast<bf16x8*>(v_t + obase + (long)d * T_ + t_base + tl) = v;
    }
  } else {
    int colp = col_base - 3 * HID;
#pragma unroll
    for (int m = 0; m < 4; m++) {
#pragma unroll
      for (int j = 0; j < 4; j++) {
        long row = row_base + m * 16 + lq * 4 + j;
#pragma unroll
        for (int n = 0; n < 4; n++)
          C5[row * K2 + HID + colp + n * 16 + l15] = f2bf(gelu_fast(acc[m][n][j]));
      }
    }
  }
}

// ---------------- GEMM2: C5 [8192,5120] @ w_outT [1024,5120] + bias -> f32 ----------------
__global__ __launch_bounds__(256) void gemm_bt(const unsigned short* __restrict__ A,
                                               const unsigned short* __restrict__ BT,
                                               float* __restrict__ Cout,
                                               const float* __restrict__ bias,
                                               int K, int lda, int ldb, int ldc) {
  __shared__ unsigned short smem2[16384];
  unsigned short* As = smem2;
  unsigned short* Bs = smem2 + 8192;
  int tid = threadIdx.x, lane = tid & 63, wid = tid >> 6;
  long row0 = (long)blockIdx.y * 128;
  long col0 = (long)blockIdx.x * 128;
  f32x4 acc[4][4] = {};
  gemm_core_db(A, BT, As, Bs, K, lda, ldb, row0, col0, lane, wid, acc);
  int wm = (wid & 1) * 64, wn = (wid >> 1) * 64;
#pragma unroll
  for (int m = 0; m < 4; m++) {
#pragma unroll
    for (int n = 0; n < 4; n++) {
      long r = row0 + wm + m * 16 + (lane >> 4) * 4;
      long c = col0 + wn + n * 16 + (lane & 15);
#pragma unroll
      for (int j = 0; j < 4; j++)
        Cout[(r + j) * (long)ldc + c] = acc[m][n][j] + bias[c];
    }
  }
}

// ---------------- flash attention: 32x32 MFMA, in-register P (R16, proven) ----------
__global__ __launch_bounds__(256) void attn_kernel(const unsigned short* __restrict__ q_r,
                                                   const unsigned short* __restrict__ k_r,
                                                   const unsigned short* __restrict__ v_t,
                                                   unsigned short* __restrict__ C5) {
  int bh = blockIdx.x;  // 0..63 (XCD-locality axis)
  int qt = blockIdx.y;  // 0..15
  int b = bh >> 4, h = bh & 15;
  int tid = threadIdx.x, lane = tid & 63, wid = tid >> 6;
  int l31 = lane & 31, hi = lane >> 5;
  __shared__ unsigned short Ks[2][64 * 64];
  __shared__ unsigned short Vts[2][64 * 64];

  const unsigned short* qbase = q_r + ((long)bh * T_ + qt * 128 + wid * 32) * 64;
  bf16x8 qf[4];
#pragma unroll
  for (int kk = 0; kk < 4; kk++)
    qf[kk] = *reinterpret_cast<const bf16x8*>(qbase + l31 * 64 + kk * 16 + hi * 8);

  f32x16 o_acc[2] = {};
  float l_run = 0.f;

  const unsigned short* kbase = k_r + (long)bh * T_ * 64;
  const unsigned short* vbase = v_t + (long)bh * 64 * T_;
  int srow = lane >> 3;
  int schnk = lane & 7;
  int slot = schnk ^ srow;

  bf16x8 kreg[2], vreg[2];
#pragma unroll
  for (int i = 0; i < 2; i++) {
    int c = wid * 2 + i;
    kreg[i] = *reinterpret_cast<const bf16x8*>(kbase + c * 512 + lane * 8);
    vreg[i] = *reinterpret_cast<const bf16x8*>(vbase + (long)(c * 8 + srow) * T_ + schnk * 8);
  }
#pragma unroll
  for (int i = 0; i < 2; i++) {
    int r = (wid * 2 + i) * 8 + srow;
    *reinterpret_cast<bf16x8*>(&Ks[0][r * 64 + slot * 8])  = kreg[i];
    *reinterpret_cast<bf16x8*>(&Vts[0][r * 64 + slot * 8]) = vreg[i];
  }
#pragma unroll
  for (int i = 0; i < 2; i++) {
    int c = wid * 2 + i;
    kreg[i] = *reinterpret_cast<const bf16x8*>(kbase + 4096 + c * 512 + lane * 8);
    vreg[i] = *reinterpret_cast<const bf16x8*>(vbase + (long)(c * 8 + srow) * T_ + 64 + schnk * 8);
  }
  __syncthreads();

  int cur = 0;
  for (int kt = 0; kt < 32; kt++) {
    if (kt < 31) {
#pragma unroll
      for (int i = 0; i < 2; i++) {
        int r = (wid * 2 + i) * 8 + srow;
        *reinterpret_cast<bf16x8*>(&Ks[cur ^ 1][r * 64 + slot * 8])  = kreg[i];
        *reinterpret_cast<bf16x8*>(&Vts[cur ^ 1][r * 64 + slot * 8]) = vreg[i];
      }
    }
    if (kt < 30) {
#pragma unroll
      for (int i = 0; i < 2; i++) {
        int c = wid * 2 + i;
        kreg[i] = *reinterpret_cast<const bf16x8*>(kbase + (kt + 2) * 4096 + c * 512 + lane * 8);
        vreg[i] = *reinterpret_cast<const bf16x8*>(vbase + (long)(c * 8 + srow) * T_ + (kt + 2) * 64 + schnk * 8);
      }
    }
    const unsigned short* Kc = Ks[cur];
    const unsigned short* Vc = Vts[cur];

    bf16x8 pa[4];
#pragma unroll
    for (int t2 = 0; t2 < 2; t2++) {
      f32x16 s2 = {};
      int krow = t2 * 32 + l31;
      __builtin_amdgcn_s_setprio(1);
#pragma unroll
      for (int kk = 0; kk < 4; kk++) {
        int c = kk * 2 + hi;
        bf16x8 kf = *reinterpret_cast<const bf16x8*>(&Kc[krow * 64 + (c ^ (krow & 7)) * 8]);
        s2 = __builtin_amdgcn_mfma_f32_32x32x16_bf16(kf, qf[kk], s2, 0, 0, 0);
      }
      __builtin_amdgcn_s_setprio(0);
      float p[16];
#pragma unroll
      for (int r = 0; r < 16; r++) p[r] = exp2f(s2[r]);
#pragma unroll
      for (int r = 0; r < 16; r++) l_run += p[r];
      unsigned int g0 = cvt_pk_bf16(p[0],  p[1]);
      unsigned int g1 = cvt_pk_bf16(p[2],  p[3]);
      unsigned int g2 = cvt_pk_bf16(p[4],  p[5]);
      unsigned int g3 = cvt_pk_bf16(p[6],  p[7]);
      unsigned int g4 = cvt_pk_bf16(p[8],  p[9]);
      unsigned int g5 = cvt_pk_bf16(p[10], p[11]);
      unsigned int g6 = cvt_pk_bf16(p[12], p[13]);
      unsigned int g7 = cvt_pk_bf16(p[14], p[15]);
      permswap(g0, g2);
      permswap(g1, g3);
      permswap(g4, g6);
      permswap(g5, g7);
      uint4 u0; u0.x = g0; u0.y = g1; u0.z = g2; u0.w = g3;
      uint4 u1; u1.x = g4; u1.y = g5; u1.z = g6; u1.w = g7;
      pa[t2 * 2]     = __builtin_bit_cast(bf16x8, u0);
      pa[t2 * 2 + 1] = __builtin_bit_cast(bf16x8, u1);
    }
    __builtin_amdgcn_s_setprio(1);
#pragma unroll
    for (int dt = 0; dt < 2; dt++) {
      int vrow = dt * 32 + l31;
#pragma unroll
      for (int kc = 0; kc < 4; kc++) {
        int c = kc * 2 + hi;
        bf16x8 vf = *reinterpret_cast<const bf16x8*>(&Vc[vrow * 64 + (c ^ (vrow & 7)) * 8]);
        o_acc[dt] = __builtin_amdgcn_mfma_f32_32x32x16_bf16(pa[kc], vf, o_acc[dt], 0, 0, 0);
      }
    }
    __builtin_amdgcn_s_setprio(0);
    __syncthreads();
    cur ^= 1;
  }
  float l = l_run;
  l += __shfl_xor(l, 32);
#pragma unroll
  for (int r = 0; r < 16; r++) {
    int qr = (r & 3) + 8 * (r >> 2) + 4 * hi;
    float inv = 1.0f / __shfl(l, qr);
    int tl = qt * 128 + wid * 32 + qr;
    long row = (long)b * T_ + tl;
#pragma unroll
    for (int dt = 0; dt < 2; dt++) {
      int col = h * 64 + dt * 32 + l31;
      C5[row * K2 + col] = f2bf(o_acc[dt][r] * inv);
    }
  }
}

extern "C" void kernel_launch(void* const* d_in, const int* in_sizes, int n_in,
                              void* d_out, int out_size, void* d_ws, size_t ws_size,
                              hipStream_t stream) {
  const float* x     = (const float*)d_in[0];
  const float* g     = (const float*)d_in[1];
  const float* be    = (const float*)d_in[2];
  const float* w_in  = (const float*)d_in[3];
  const float* w_out = (const float*)d_in[4];
  const float* b_out = (const float*)d_in[5];
  float* out = (float*)d_out;

  char* ws = (char*)d_ws;
  size_t off = 0;
  auto alloc = [&](size_t bytes) {
    void* p = ws + off;
    off += (bytes + 255) & ~(size_t)255;
    return p;
  };
  unsigned short* xn     = (unsigned short*)alloc((size_t)BT_ * HID * 2);
  unsigned short* w_inT  = (unsigned short*)alloc((size_t)N1 * HID * 2);
  unsigned short* w_outT = (unsigned short*)alloc((size_t)HID * K2 * 2);
  unsigned short* q_rb   = (unsigned short*)alloc((size_t)BT_ * HID * 2);
  unsigned short* k_rb   = (unsigned short*)alloc((size_t)BT_ * HID * 2);
  unsigned short* v_tb   = (unsigned short*)alloc((size_t)BT_ * HID * 2);
  unsigned short* C5     = (unsigned short*)alloc((size_t)BT_ * K2 * 2);

  tcast_kernel<<<dim3(N1 / 64, HID / 64), 256, 0, stream>>>(w_in, w_inT, HID, N1);
  tcast_kernel<<<dim3(HID / 64, K2 / 64), 256, 0, stream>>>(w_out, w_outT, K2, HID);
  ln_kernel<<<BT_, 256, 0, stream>>>(x, g, be, xn);
  gemm1_fused<<<dim3(N1 / 128, BT_ / 128), 256, 0, stream>>>(xn, w_inT, q_rb, k_rb, v_tb, C5);
  attn_kernel<<<dim3(64, T_ / 128), 256, 0, stream>>>(q_rb, k_rb, v_tb, C5);
  gemm_bt<<<dim3(HID / 128, BT_ / 128), 256, 0, stream>>>(C5, w_outT, out, b_out,
                                                          K2, K2, K2, HID);
}

// Round 19
// 403.989 us; speedup vs baseline: 1.0241x; 1.0241x over previous
//
#include <hip/hip_runtime.h>
#include <hip/hip_bf16.h>
#include <math.h>

typedef short bf16x8 __attribute__((ext_vector_type(8)));
typedef float f32x4 __attribute__((ext_vector_type(4)));
typedef float f32x16 __attribute__((ext_vector_type(16)));

#define HEADS 16
#define HDIM 64
#define HID 1024
#define B_ 4
#define T_ 2048
#define BT_ (B_*T_)      /* 8192 */
#define N1 (7*HID)       /* 7168 */
#define K2 (5*HID)       /* 5120 */

#define SM_SCALE_LOG2E 0.18033688011111793f   /* 0.125 * log2(e), folded into q at gemm1 */

__device__ __forceinline__ float bf2f(unsigned short u) {
  union { unsigned int i; float f; } c; c.i = ((unsigned int)u) << 16; return c.f;
}
__device__ __forceinline__ unsigned short f2bf(float f) {
  __hip_bfloat16 h = __float2bfloat16(f);
  return __builtin_bit_cast(unsigned short, h);
}
__device__ __forceinline__ unsigned int cvt_pk_bf16(float a, float b) {
  unsigned int r;
  asm("v_cvt_pk_bf16_f32 %0, %1, %2" : "=v"(r) : "v"(a), "v"(b));
  return r;
}
// v_permlane32_swap_b32: D.lanes[32:63] <-> S.lanes[0:31]; writes BOTH regs.
__device__ __forceinline__ void permswap(unsigned int& d, unsigned int& s) {
  asm volatile("v_permlane32_swap_b32 %0, %1" : "+v"(d), "+v"(s));
}
__device__ __forceinline__ float gelu_fast(float x) {
  float y = 0.7978845608028654f * (x + 0.044715f * x * x * x);
  float e = exp2f(y * 2.8853900817779268f);       // exp(2y)
  float t = 1.f - 2.f / (e + 1.f);                 // tanh(y)
  return 0.5f * x * (1.f + t);
}

typedef __attribute__((address_space(1))) const unsigned int gu32;
typedef __attribute__((address_space(3))) unsigned int lu32;
__device__ __forceinline__ void async16(const void* g, void* l) {
  __builtin_amdgcn_global_load_lds((gu32*)g, (lu32*)l, 16, 0, 0);
}

// ---------------- transpose + cast: in [R][C] f32 -> out [C][R] bf16 ----------------
__global__ __launch_bounds__(256) void tcast_kernel(const float* __restrict__ in,
                                                    unsigned short* __restrict__ out,
                                                    int R, int C) {
  __shared__ float tile[64][65];
  int tx = threadIdx.x & 63;
  int ty = threadIdx.x >> 6;
  long r0 = (long)blockIdx.y * 64;
  long c0 = (long)blockIdx.x * 64;
#pragma unroll
  for (int i = 0; i < 16; i++) {
    int r = ty + i * 4;
    tile[r][tx] = in[(r0 + r) * C + c0 + tx];
  }
  __syncthreads();
#pragma unroll
  for (int i = 0; i < 16; i++) {
    int rr = ty + i * 4;
    out[(c0 + rr) * R + r0 + tx] = f2bf(tile[tx][rr]);
  }
}

// ---------------- LayerNorm f32 -> bf16 ----------------
__global__ __launch_bounds__(256) void ln_kernel(const float* __restrict__ x,
                                                 const float* __restrict__ g,
                                                 const float* __restrict__ b,
                                                 unsigned short* __restrict__ xn) {
  int row = blockIdx.x, tid = threadIdx.x;
  float4 v = reinterpret_cast<const float4*>(x + (long)row * HID)[tid];
  float s = v.x + v.y + v.z + v.w;
  float sq = v.x * v.x + v.y * v.y + v.z * v.z + v.w * v.w;
#pragma unroll
  for (int off = 32; off > 0; off >>= 1) { s += __shfl_down(s, off); sq += __shfl_down(sq, off); }
  __shared__ float red[8];
  int wid = tid >> 6, lane = tid & 63;
  if (lane == 0) { red[wid] = s; red[4 + wid] = sq; }
  __syncthreads();
  if (tid == 0) {
    red[0] = red[0] + red[1] + red[2] + red[3];
    red[4] = red[4] + red[5] + red[6] + red[7];
  }
  __syncthreads();
  float mean = red[0] * (1.f / HID);
  float var  = red[4] * (1.f / HID) - mean * mean;
  float rstd = rsqrtf(var + 1e-5f);
  float4 gv = reinterpret_cast<const float4*>(g)[tid];
  float4 bv = reinterpret_cast<const float4*>(b)[tid];
  ushort4 o;
  o.x = f2bf((v.x - mean) * rstd * gv.x + bv.x);
  o.y = f2bf((v.y - mean) * rstd * gv.y + bv.y);
  o.z = f2bf((v.z - mean) * rstd * gv.z + bv.z);
  o.w = f2bf((v.w - mean) * rstd * gv.w + bv.w);
  reinterpret_cast<ushort4*>(xn + (long)row * HID)[tid] = o;
}

// ---------------- GEMM core: 128x128, BK=32, T3+T4 schedule ----------------
// DMA staging (global_load_lds w=16, R14-verified addressing: linear LDS dest lane l ->
// row R0+(l>>2) slot l&3, inverse-swizzled source chunk (l&3)^((l>>3)&3) -> LDS slot s
// of row r holds chunk s^((r>>1)&3), matching the fragment-read swizzle). TRIPLE-buffer
// + counted vmcnt: DMA tile t+2 issued at iter t; barrier waits only vmcnt(4) (tile
// t+1's 4-op-old DMAs, in-order counter semantics) -- never drains the fresh DMAs
// (R14's vmcnt(0) pathology). lgkmcnt(0) in the same wait orders ds_reads before the
// next iter's DMA overwrite of the just-read buffer. Raw s_barrier + sched_barrier(0)
// per guide rule #18. Deletes all ds_writes: LDS pipe 2300 -> 1536 cy/CU-round.
__device__ __forceinline__ void gemm_core_t34(const unsigned short* __restrict__ A,
                                              const unsigned short* __restrict__ BT,
                                              unsigned short* As, unsigned short* Bs,
                                              int K, int lda, int ldb,
                                              long row0, long col0,
                                              int lane, int wid, f32x4 (&acc)[4][4]) {
  int l15 = lane & 15, lq = lane >> 4;
  int d  = lane >> 2;                       // row within 16-row segment
  int ch = (lane & 3) ^ ((lane >> 3) & 3);  // inverse-swizzled source chunk
  int R0 = wid * 32;
  const unsigned short* aS0 = A + (row0 + R0 + d)      * (long)lda + ch * 8;
  const unsigned short* aS1 = A + (row0 + R0 + 16 + d) * (long)lda + ch * 8;
  const unsigned short* bS0 = BT + (col0 + R0 + d)      * (long)ldb + ch * 8;
  const unsigned short* bS1 = BT + (col0 + R0 + 16 + d) * (long)ldb + ch * 8;
  int wm = (wid & 1) * 64, wn = (wid >> 1) * 64;
  const int NT = K / 32;

  unsigned short* A0 = As;         unsigned short* B0 = Bs;
  unsigned short* A1 = As + 4096;  unsigned short* B1 = Bs + 4096;
  unsigned short* A2 = As + 8192;  unsigned short* B2 = Bs + 8192;

  // prologue: DMA tiles 0 and 1 (8 ops); wait tile 0 (oldest 4) only
  async16(aS0, &A0[R0 * 32]);
  async16(aS1, &A0[(R0 + 16) * 32]);
  async16(bS0, &B0[R0 * 32]);
  async16(bS1, &B0[(R0 + 16) * 32]);
  async16(aS0 + 32, &A1[R0 * 32]);
  async16(aS1 + 32, &A1[(R0 + 16) * 32]);
  async16(bS0 + 32, &B1[R0 * 32]);
  async16(bS1 + 32, &B1[(R0 + 16) * 32]);
  asm volatile("s_waitcnt vmcnt(4)" ::: "memory");
  __builtin_amdgcn_s_barrier();
  __builtin_amdgcn_sched_barrier(0);

  for (int t = 0; t < NT; t++) {
    // issue DMA for tile t+2 into the buffer whose reads finished at iter t-1
    if (t + 2 < NT) {
      long ko = (long)(t + 2) * 32;
      async16(aS0 + ko, &A2[R0 * 32]);
      async16(aS1 + ko, &A2[(R0 + 16) * 32]);
      async16(bS0 + ko, &B2[R0 * 32]);
      async16(bS1 + ko, &B2[(R0 + 16) * 32]);
    }
    bf16x8 af[4], bfv[4];
#pragma unroll
    for (int m = 0; m < 4; m++) {
      int r = wm + m * 16 + l15;
      af[m] = *reinterpret_cast<const bf16x8*>(&A0[r * 32 + (lq ^ ((r >> 1) & 3)) * 8]);
    }
#pragma unroll
    for (int n = 0; n < 4; n++) {
      int r = wn + n * 16 + l15;
      bfv[n] = *reinterpret_cast<const bf16x8*>(&B0[r * 32 + (lq ^ ((r >> 1) & 3)) * 8]);
    }
#pragma unroll
    for (int m = 0; m < 4; m++)
#pragma unroll
      for (int n = 0; n < 4; n++)
        acc[m][n] = __builtin_amdgcn_mfma_f32_16x16x32_bf16(af[m], bfv[n], acc[m][n], 0, 0, 0);
    // counted wait: ensure tile t+1 landed (oldest 4 of <=8 outstanding) and our
    // ds_reads completed (lgkm) before anyone overwrites this buffer next iter.
    if (t + 2 < NT) {
      asm volatile("s_waitcnt vmcnt(4) lgkmcnt(0)" ::: "memory");
    } else {
      asm volatile("s_waitcnt vmcnt(0) lgkmcnt(0)" ::: "memory");
    }
    __builtin_amdgcn_s_barrier();
    __builtin_amdgcn_sched_barrier(0);
    unsigned short* ta = A0; A0 = A1; A1 = A2; A2 = ta;
    unsigned short* tb = B0; B0 = B1; B1 = B2; B2 = tb;
  }
}

// ---------------- GEMM1 with fused rotary / V-transpose / GELU epilogue ----------
__global__ __launch_bounds__(256) void gemm1_fused(const unsigned short* __restrict__ A,
                                                   const unsigned short* __restrict__ BT,
                                                   unsigned short* __restrict__ q_r,
                                                   unsigned short* __restrict__ k_r,
                                                   unsigned short* __restrict__ v_t,
                                                   unsigned short* __restrict__ C5) {
  __shared__ unsigned short smem[24576];   // 48KB: A/B triple-buffers; reused for Vt
  unsigned short* As = smem;               // [3][128][32]
  unsigned short* Bs = smem + 12288;       // [3][128][32]
  int tid = threadIdx.x, lane = tid & 63, wid = tid >> 6;
  long row0 = (long)blockIdx.y * 128;
  long col0 = (long)blockIdx.x * 128;
  f32x4 acc[4][4] = {};
  gemm_core_t34(A, BT, As, Bs, HID, HID, HID, row0, col0, lane, wid, acc);
  // loop ends with full drain + barrier -> smem reusable

  int wm = (wid & 1) * 64, wn = (wid >> 1) * 64;
  long row_base = row0 + wm;
  int b = (int)(row_base >> 11);
  int t_base = (int)(row_base & 2047);
  int col_base = (int)col0 + wn;
  int region = col_base >> 10;
  int l15 = lane & 15, lq = lane >> 4;

  if (region <= 1) {
    unsigned short* dst = (region == 0) ? q_r : k_r;
    float osc = (region == 0) ? SM_SCALE_LOG2E : 1.0f;
    int head = (col_base & 1023) >> 6;
    long obase = (long)(b * 16 + head) * T_ * 64;
    float fr[2];
    fr[0] = __expf(-(float)l15 * 0.28782313662425572f);
    fr[1] = __expf(-(float)(16 + l15) * 0.28782313662425572f);
#pragma unroll
    for (int m = 0; m < 4; m++) {
#pragma unroll
      for (int j = 0; j < 4; j++) {
        int t = t_base + m * 16 + lq * 4 + j;
#pragma unroll
        for (int n = 0; n < 2; n++) {
          float sn, cs;
          __sincosf((float)t * fr[n], &sn, &cs);
          float xl = acc[m][n][j], xh = acc[m][n + 2][j];
          int dd = n * 16 + l15;
          dst[obase + (long)t * 64 + dd]      = f2bf((xl * cs - xh * sn) * osc);
          dst[obase + (long)t * 64 + dd + 32] = f2bf((xl * sn + xh * cs) * osc);
        }
      }
    }
  } else if (region == 2) {
    int head = (col_base & 1023) >> 6;
    unsigned short* vt = smem + wid * 4608;
#pragma unroll
    for (int m = 0; m < 4; m++)
#pragma unroll
      for (int n = 0; n < 4; n++)
#pragma unroll
        for (int j = 0; j < 4; j++)
          vt[(n * 16 + l15) * 72 + m * 16 + lq * 4 + j] = f2bf(acc[m][n][j]);
    long obase = (long)(b * 16 + head) * 64 * T_;
#pragma unroll
    for (int i = 0; i < 8; i++) {
      int dd = i * 8 + (lane >> 3);
      int tl = (lane & 7) * 8;
      bf16x8 v = *reinterpret_cast<const bf16x8*>(&vt[dd * 72 + tl]);
      *reinterpret_cast<bf16x8*>(v_t + obase + (long)dd * T_ + t_base + tl) = v;
    }
  } else {
    int colp = col_base - 3 * HID;
#pragma unroll
    for (int m = 0; m < 4; m++) {
#pragma unroll
      for (int j = 0; j < 4; j++) {
        long row = row_base + m * 16 + lq * 4 + j;
#pragma unroll
        for (int n = 0; n < 4; n++)
          C5[row * K2 + HID + colp + n * 16 + l15] = f2bf(gelu_fast(acc[m][n][j]));
      }
    }
  }
}

// ---------------- GEMM2: C5 [8192,5120] @ w_outT [1024,5120] + bias -> f32 ----------------
__global__ __launch_bounds__(256) void gemm_bt(const unsigned short* __restrict__ A,
                                               const unsigned short* __restrict__ BT,
                                               float* __restrict__ Cout,
                                               const float* __restrict__ bias,
                                               int K, int lda, int ldb, int ldc) {
  __shared__ unsigned short smem2[24576];
  unsigned short* As = smem2;
  unsigned short* Bs = smem2 + 12288;
  int tid = threadIdx.x, lane = tid & 63, wid = tid >> 6;
  long row0 = (long)blockIdx.y * 128;
  long col0 = (long)blockIdx.x * 128;
  f32x4 acc[4][4] = {};
  gemm_core_t34(A, BT, As, Bs, K, lda, ldb, row0, col0, lane, wid, acc);
  int wm = (wid & 1) * 64, wn = (wid >> 1) * 64;
#pragma unroll
  for (int m = 0; m < 4; m++) {
#pragma unroll
    for (int n = 0; n < 4; n++) {
      long r = row0 + wm + m * 16 + (lane >> 4) * 4;
      long c = col0 + wn + n * 16 + (lane & 15);
#pragma unroll
      for (int j = 0; j < 4; j++)
        Cout[(r + j) * (long)ldc + c] = acc[m][n][j] + bias[c];
    }
  }
}

// ---------------- flash attention: 32x32 MFMA, in-register P (R16/R18, proven) ------
__global__ __launch_bounds__(256) void attn_kernel(const unsigned short* __restrict__ q_r,
                                                   const unsigned short* __restrict__ k_r,
                                                   const unsigned short* __restrict__ v_t,
                                                   unsigned short* __restrict__ C5) {
  int bh = blockIdx.x;  // 0..63 (XCD-locality axis)
  int qt = blockIdx.y;  // 0..15
  int b = bh >> 4, h = bh & 15;
  int tid = threadIdx.x, lane = tid & 63, wid = tid >> 6;
  int l31 = lane & 31, hi = lane >> 5;
  __shared__ unsigned short Ks[2][64 * 64];
  __shared__ unsigned short Vts[2][64 * 64];

  const unsigned short* qbase = q_r + ((long)bh * T_ + qt * 128 + wid * 32) * 64;
  bf16x8 qf[4];
#pragma unroll
  for (int kk = 0; kk < 4; kk++)
    qf[kk] = *reinterpret_cast<const bf16x8*>(qbase + l31 * 64 + kk * 16 + hi * 8);

  f32x16 o_acc[2] = {};
  float l_run = 0.f;

  const unsigned short* kbase = k_r + (long)bh * T_ * 64;
  const unsigned short* vbase = v_t + (long)bh * 64 * T_;
  int srow = lane >> 3;
  int schnk = lane & 7;
  int slot = schnk ^ srow;

  bf16x8 kreg[2], vreg[2];
#pragma unroll
  for (int i = 0; i < 2; i++) {
    int c = wid * 2 + i;
    kreg[i] = *reinterpret_cast<const bf16x8*>(kbase + c * 512 + lane * 8);
    vreg[i] = *reinterpret_cast<const bf16x8*>(vbase + (long)(c * 8 + srow) * T_ + schnk * 8);
  }
#pragma unroll
  for (int i = 0; i < 2; i++) {
    int r = (wid * 2 + i) * 8 + srow;
    *reinterpret_cast<bf16x8*>(&Ks[0][r * 64 + slot * 8])  = kreg[i];
    *reinterpret_cast<bf16x8*>(&Vts[0][r * 64 + slot * 8]) = vreg[i];
  }
#pragma unroll
  for (int i = 0; i < 2; i++) {
    int c = wid * 2 + i;
    kreg[i] = *reinterpret_cast<const bf16x8*>(kbase + 4096 + c * 512 + lane * 8);
    vreg[i] = *reinterpret_cast<const bf16x8*>(vbase + (long)(c * 8 + srow) * T_ + 64 + schnk * 8);
  }
  __syncthreads();

  int cur = 0;
  for (int kt = 0; kt < 32; kt++) {
    if (kt < 31) {
#pragma unroll
      for (int i = 0; i < 2; i++) {
        int r = (wid * 2 + i) * 8 + srow;
        *reinterpret_cast<bf16x8*>(&Ks[cur ^ 1][r * 64 + slot * 8])  = kreg[i];
        *reinterpret_cast<bf16x8*>(&Vts[cur ^ 1][r * 64 + slot * 8]) = vreg[i];
      }
    }
    if (kt < 30) {
#pragma unroll
      for (int i = 0; i < 2; i++) {
        int c = wid * 2 + i;
        kreg[i] = *reinterpret_cast<const bf16x8*>(kbase + (kt + 2) * 4096 + c * 512 + lane * 8);
        vreg[i] = *reinterpret_cast<const bf16x8*>(vbase + (long)(c * 8 + srow) * T_ + (kt + 2) * 64 + schnk * 8);
      }
    }
    const unsigned short* Kc = Ks[cur];
    const unsigned short* Vc = Vts[cur];

    bf16x8 pa[4];
#pragma unroll
    for (int t2 = 0; t2 < 2; t2++) {
      f32x16 s2 = {};
      int krow = t2 * 32 + l31;
      __builtin_amdgcn_s_setprio(1);
#pragma unroll
      for (int kk = 0; kk < 4; kk++) {
        int c = kk * 2 + hi;
        bf16x8 kf = *reinterpret_cast<const bf16x8*>(&Kc[krow * 64 + (c ^ (krow & 7)) * 8]);
        s2 = __builtin_amdgcn_mfma_f32_32x32x16_bf16(kf, qf[kk], s2, 0, 0, 0);
      }
      __builtin_amdgcn_s_setprio(0);
      float p[16];
#pragma unroll
      for (int r = 0; r < 16; r++) p[r] = exp2f(s2[r]);
#pragma unroll
      for (int r = 0; r < 16; r++) l_run += p[r];
      unsigned int g0 = cvt_pk_bf16(p[0],  p[1]);
      unsigned int g1 = cvt_pk_bf16(p[2],  p[3]);
      unsigned int g2 = cvt_pk_bf16(p[4],  p[5]);
      unsigned int g3 = cvt_pk_bf16(p[6],  p[7]);
      unsigned int g4 = cvt_pk_bf16(p[8],  p[9]);
      unsigned int g5 = cvt_pk_bf16(p[10], p[11]);
      unsigned int g6 = cvt_pk_bf16(p[12], p[13]);
      unsigned int g7 = cvt_pk_bf16(p[14], p[15]);
      permswap(g0, g2);
      permswap(g1, g3);
      permswap(g4, g6);
      permswap(g5, g7);
      uint4 u0; u0.x = g0; u0.y = g1; u0.z = g2; u0.w = g3;
      uint4 u1; u1.x = g4; u1.y = g5; u1.z = g6; u1.w = g7;
      pa[t2 * 2]     = __builtin_bit_cast(bf16x8, u0);
      pa[t2 * 2 + 1] = __builtin_bit_cast(bf16x8, u1);
    }
    __builtin_amdgcn_s_setprio(1);
#pragma unroll
    for (int dt = 0; dt < 2; dt++) {
      int vrow = dt * 32 + l31;
#pragma unroll
      for (int kc = 0; kc < 4; kc++) {
        int c = kc * 2 + hi;
        bf16x8 vf = *reinterpret_cast<const bf16x8*>(&Vc[vrow * 64 + (c ^ (vrow & 7)) * 8]);
        o_acc[dt] = __builtin_amdgcn_mfma_f32_32x32x16_bf16(pa[kc], vf, o_acc[dt], 0, 0, 0);
      }
    }
    __builtin_amdgcn_s_setprio(0);
    __syncthreads();
    cur ^= 1;
  }
  float l = l_run;
  l += __shfl_xor(l, 32);
#pragma unroll
  for (int r = 0; r < 16; r++) {
    int qr = (r & 3) + 8 * (r >> 2) + 4 * hi;
    float inv = 1.0f / __shfl(l, qr);
    int tl = qt * 128 + wid * 32 + qr;
    long row = (long)b * T_ + tl;
#pragma unroll
    for (int dt = 0; dt < 2; dt++) {
      int col = h * 64 + dt * 32 + l31;
      C5[row * K2 + col] = f2bf(o_acc[dt][r] * inv);
    }
  }
}

extern "C" void kernel_launch(void* const* d_in, const int* in_sizes, int n_in,
                              void* d_out, int out_size, void* d_ws, size_t ws_size,
                              hipStream_t stream) {
  const float* x     = (const float*)d_in[0];
  const float* g     = (const float*)d_in[1];
  const float* be    = (const float*)d_in[2];
  const float* w_in  = (const float*)d_in[3];
  const float* w_out = (const float*)d_in[4];
  const float* b_out = (const float*)d_in[5];
  float* out = (float*)d_out;

  char* ws = (char*)d_ws;
  size_t off = 0;
  auto alloc = [&](size_t bytes) {
    void* p = ws + off;
    off += (bytes + 255) & ~(size_t)255;
    return p;
  };
  unsigned short* xn     = (unsigned short*)alloc((size_t)BT_ * HID * 2);
  unsigned short* w_inT  = (unsigned short*)alloc((size_t)N1 * HID * 2);
  unsigned short* w_outT = (unsigned short*)alloc((size_t)HID * K2 * 2);
  unsigned short* q_rb   = (unsigned short*)alloc((size_t)BT_ * HID * 2);
  unsigned short* k_rb   = (unsigned short*)alloc((size_t)BT_ * HID * 2);
  unsigned short* v_tb   = (unsigned short*)alloc((size_t)BT_ * HID * 2);
  unsigned short* C5     = (unsigned short*)alloc((size_t)BT_ * K2 * 2);

  tcast_kernel<<<dim3(N1 / 64, HID / 64), 256, 0, stream>>>(w_in, w_inT, HID, N1);
  tcast_kernel<<<dim3(HID / 64, K2 / 64), 256, 0, stream>>>(w_out, w_outT, K2, HID);
  ln_kernel<<<BT_, 256, 0, stream>>>(x, g, be, xn);
  gemm1_fused<<<dim3(N1 / 128, BT_ / 128), 256, 0, stream>>>(xn, w_inT, q_rb, k_rb, v_tb, C5);
  attn_kernel<<<dim3(64, T_ / 128), 256, 0, stream>>>(q_rb, k_rb, v_tb, C5);
  gemm_bt<<<dim3(HID / 128, BT_ / 128), 256, 0, stream>>>(C5, w_outT, out, b_out,
                                                          K2, K2, K2, HID);
}